// Round 13
// baseline (131.223 us; speedup 1.0000x reference)
//
#include <hip/hip_runtime.h>
#include <hip/hip_bf16.h>
#include <math.h>

#define NSEQ 4096
#define TN 288
#define EPSF 1e-5f

typedef short bf16x8 __attribute__((ext_vector_type(8)));
typedef float f32x4 __attribute__((ext_vector_type(4)));

// ---- d_ws layout (shorts): preconverted bf16 weights ----
#define WSV 0        // Wv 16x16
#define WSK 256      // Wk 16x16
#define WSQ 512      // Wq 16x16  (PRE-SCALED by 0.125 = 1/sqrt(E))
#define WSO 768      // Wo 64x64 row-major
#define WS1 4864     // W1 256x64 row-major
#define WS2 21248    // W2 64x256 row-major

// ---- LDS pool: 27136 B ----
//  A [0,3456)      qbf [48][72] (INTACT until LN1) -> xbf (per-wave rows)
//  B [3456,6912)   kbf -> kp (P1 in-place) -> o (P2P3, per-head cols)
//  C [6912,10496)  vbf [48][72] -> qp-compact 4x[48][16] (after barrier 1)
//  D [10496,13568) vpT [64][48] -> att per-head [16][48] (own slice)
//  H [6912,13440)  h [48][136] (FF, rows per-wave; over C+D after P2P3)
#define A_S   0
#define B_S   3456
#define C_S   6912
#define D_S   10496
#define H_S   6912

__device__ __forceinline__ unsigned short f2bf_u(float f) {
    __hip_bfloat16 h = __float2bfloat16(f);
    return *reinterpret_cast<const unsigned short*>(&h);
}
__device__ __forceinline__ unsigned int pk2(float a, float b) {
    return (unsigned int)f2bf_u(a) | ((unsigned int)f2bf_u(b) << 16);
}
__device__ __forceinline__ float bits2f(unsigned int u) { return __uint_as_float(u); }

// ---------- prologue: f32 -> bf16 weight conversion into d_ws ----------
__global__ void wconv_kernel(const float* __restrict__ Wv, const float* __restrict__ Wk,
                             const float* __restrict__ Wq, const float* __restrict__ Wo,
                             const float* __restrict__ W1, const float* __restrict__ W2,
                             short* __restrict__ ws) {
    int i = blockIdx.x * 256 + threadIdx.x;   // 0..37631
    float v;
    if (i < 256)        v = Wv[i];
    else if (i < 512)   v = Wk[i - 256];
    else if (i < 768)   v = Wq[i - 512] * 0.125f;   // fold 1/sqrt(E) into Wq
    else if (i < 4864)  v = Wo[i - 768];
    else if (i < 21248) v = W1[i - 4864];
    else                v = W2[i - 21248];
    ws[i] = (short)f2bf_u(v);
}

__global__ __launch_bounds__(256, 5)
void ttrans_kernel(const float* __restrict__ value,
                   const float* __restrict__ keys,
                   const float* __restrict__ query,
                   const float* __restrict__ bo,
                   const float* __restrict__ temb,
                   const float* __restrict__ ln1g,
                   const float* __restrict__ ln1b,
                   const float* __restrict__ ln2g,
                   const float* __restrict__ ln2b,
                   const float* __restrict__ pb1,
                   const float* __restrict__ pb2,
                   const short* __restrict__ ws,
                   const int* __restrict__ tqp,
                   float* __restrict__ out)
{
    __shared__ __align__(16) unsigned char smem[27136];
    short* S16 = reinterpret_cast<short*>(smem);

    const int tid  = threadIdx.x;
    const int lane = tid & 63;
    const int w    = tid >> 6;           // wave 0..3 (= head in P1-P3)
    const int l15  = lane & 15;
    const int lg   = lane >> 4;
    const int n    = blockIdx.x;
    const size_t gbase = (size_t)n * 3072;
    const int tqv  = *tqp;
    const int c4   = (lane & 15) * 4;
    const int rg   = lane >> 4;
    const int hh   = w;

    // ================= P0: coalesced float4 load q,k,v (+temb) -> bf16 LDS
    {
        int t = w * 12 + rg;
        int ti = ((tqv % TN) + TN + t) % TN;
        #pragma unroll
        for (int it = 0; it < 3; ++it) {
            float4 tv = *reinterpret_cast<const float4*>(&temb[ti * 64 + c4]);
            float4 qv = *reinterpret_cast<const float4*>(&query[gbase + t * 64 + c4]);
            float4 kv = *reinterpret_cast<const float4*>(&keys [gbase + t * 64 + c4]);
            float4 vv = *reinterpret_cast<const float4*>(&value[gbase + t * 64 + c4]);
            float4 qq = make_float4(qv.x + tv.x, qv.y + tv.y, qv.z + tv.z, qv.w + tv.w);
            float4 kk = make_float4(kv.x + tv.x, kv.y + tv.y, kv.z + tv.z, kv.w + tv.w);
            *reinterpret_cast<uint2*>(&S16[A_S + t * 72 + c4]) =
                make_uint2(pk2(qq.x, qq.y), pk2(qq.z, qq.w));
            *reinterpret_cast<uint2*>(&S16[B_S + t * 72 + c4]) =
                make_uint2(pk2(kk.x, kk.y), pk2(kk.z, kk.w));
            *reinterpret_cast<uint2*>(&S16[C_S + t * 72 + c4]) =
                make_uint2(pk2(vv.x, vv.y), pk2(vv.z, vv.w));
            t += 4; ti += 4; if (ti >= TN) ti -= TN;
        }
    }
    __syncthreads();   // (0)

    // ================= P1: per-head projections. kp in-place over kbf,
    // vpT -> D, qp HELD IN REGISTERS (qbf in A stays intact for residual).
    f32x4 cQ[3];
    {
        bf16x8 bWv = {}, bWk = {}, bWq = {};
        if (lane < 32) {
            bWv = *reinterpret_cast<const bf16x8*>(&ws[WSV + l15 * 16 + lg * 8]);
            bWk = *reinterpret_cast<const bf16x8*>(&ws[WSK + l15 * 16 + lg * 8]);
            bWq = *reinterpret_cast<const bf16x8*>(&ws[WSQ + l15 * 16 + lg * 8]);
        }
        #pragma unroll
        for (int rt = 0; rt < 3; ++rt) {
            bf16x8 aQ = {}, aK = {}, aV = {};
            if (lane < 32) {
                int ro = (rt * 16 + l15) * 72 + hh * 16 + lg * 8;
                aQ = *reinterpret_cast<const bf16x8*>(&S16[A_S + ro]);
                aK = *reinterpret_cast<const bf16x8*>(&S16[B_S + ro]);
                aV = *reinterpret_cast<const bf16x8*>(&S16[C_S + ro]);
            }
            f32x4 z = {0.f,0.f,0.f,0.f};
            cQ[rt] = __builtin_amdgcn_mfma_f32_16x16x32_bf16(aQ, bWq, z, 0, 0, 0);
            f32x4 cK = __builtin_amdgcn_mfma_f32_16x16x32_bf16(aK, bWk, z, 0, 0, 0);
            f32x4 cV = __builtin_amdgcn_mfma_f32_16x16x32_bf16(aV, bWv, z, 0, 0, 0);
            #pragma unroll
            for (int r = 0; r < 4; ++r) {
                int row = rt * 16 + lg * 4 + r;
                S16[B_S + row * 72 + hh * 16 + l15] = (short)f2bf_u(cK[r]);
                S16[D_S + (hh * 16 + l15) * 48 + row] = (short)f2bf_u(cV[r]);
            }
        }
    }
    __syncthreads();   // (1) vbf (C) fully consumed; qp/att writes now safe

    // ================= P2+P3: qp -> C compact [48][16]/head; att -> D over
    // own vpT slice (vA/vB pre-loaded). Causal skip + defer-normalize (r11).
    {
        const float PEXP = 0.006737946999085467f;            // e^-5
        const unsigned short PBF = f2bf_u(PEXP);
        // qp-compact store (own head region, same-wave read later)
        #pragma unroll
        for (int rt = 0; rt < 3; ++rt)
            #pragma unroll
            for (int r = 0; r < 4; ++r)
                S16[C_S + hh * 768 + (rt * 16 + lg * 4 + r) * 16 + l15] =
                    (short)f2bf_u(cQ[rt][r]);
        bf16x8 bK0 = {}, bK1 = {}, bK2 = {};
        if (lane < 32) {
            bK0 = *reinterpret_cast<const bf16x8*>(&S16[B_S + ( 0 + l15) * 72 + hh * 16 + lg * 8]);
            bK1 = *reinterpret_cast<const bf16x8*>(&S16[B_S + (16 + l15) * 72 + hh * 16 + lg * 8]);
            bK2 = *reinterpret_cast<const bf16x8*>(&S16[B_S + (32 + l15) * 72 + hh * 16 + lg * 8]);
        }
        bf16x8 vA = *reinterpret_cast<const bf16x8*>(&S16[D_S + (hh * 16 + l15) * 48 + lg * 8]);
        bf16x8 vB = {};
        if (lane < 32)
            vB = *reinterpret_cast<const bf16x8*>(&S16[D_S + (hh * 16 + l15) * 48 + 32 + lg * 8]);

        #pragma unroll
        for (int rt = 0; rt < 3; ++rt) {
            bf16x8 aQ = {};
            if (lane < 32)
                aQ = *reinterpret_cast<const bf16x8*>(&S16[C_S + hh * 768 + (rt * 16 + l15) * 16 + lg * 8]);
            f32x4 z = {0.f,0.f,0.f,0.f};
            f32x4 e0 = __builtin_amdgcn_mfma_f32_16x16x32_bf16(aQ, bK0, z, 0, 0, 0);
            f32x4 e1 = z, e2 = z;
            if (rt >= 1) e1 = __builtin_amdgcn_mfma_f32_16x16x32_bf16(aQ, bK1, z, 0, 0, 0);
            if (rt == 2) e2 = __builtin_amdgcn_mfma_f32_16x16x32_bf16(aQ, bK2, z, 0, 0, 0);
            const int abase = D_S + hh * 768;    // att [16][48] over own vpT
            float inv[4];
            #pragma unroll
            for (int r = 0; r < 4; ++r) {
                int tl = lg * 4 + r;
                int t = rt * 16 + tl;
                float p0, p1, p2;
                float v0 = fminf(5.f, fmaxf(-5.f, e0[r]));
                if (rt == 0) v0 = (l15 <= t) ? v0 : -5.f;
                p0 = __expf(v0);
                S16[abase + tl * 48 + l15] = (short)f2bf_u(p0);
                if (rt == 0) {
                    p1 = PEXP;
                    S16[abase + tl * 48 + 16 + l15] = (short)PBF;
                } else {
                    float v1 = fminf(5.f, fmaxf(-5.f, e1[r]));
                    if (rt == 1) v1 = (16 + l15 <= t) ? v1 : -5.f;
                    p1 = __expf(v1);
                    S16[abase + tl * 48 + 16 + l15] = (short)f2bf_u(p1);
                }
                if (rt < 2) {
                    p2 = PEXP;
                    S16[abase + tl * 48 + 32 + l15] = (short)PBF;
                } else {
                    float v2c = fminf(5.f, fmaxf(-5.f, e2[r]));
                    v2c = (32 + l15 <= t) ? v2c : -5.f;
                    p2 = __expf(v2c);
                    S16[abase + tl * 48 + 32 + l15] = (short)f2bf_u(p2);
                }
                float s = p0 + p1 + p2;
                s += __shfl_xor(s, 1);
                s += __shfl_xor(s, 2);
                s += __shfl_xor(s, 4);
                s += __shfl_xor(s, 8);
                inv[r] = __builtin_amdgcn_rcpf(s);
            }
            bf16x8 a0 = *reinterpret_cast<const bf16x8*>(&S16[abase + l15 * 48 + lg * 8]);
            bf16x8 a1 = {};
            if (lane < 32)
                a1 = *reinterpret_cast<const bf16x8*>(&S16[abase + l15 * 48 + 32 + lg * 8]);
            f32x4 zz = {0.f,0.f,0.f,0.f};
            f32x4 oc = __builtin_amdgcn_mfma_f32_16x16x32_bf16(a0, vA, zz, 0, 0, 0);
            oc = __builtin_amdgcn_mfma_f32_16x16x32_bf16(a1, vB, oc, 0, 0, 0);
            #pragma unroll
            for (int r = 0; r < 4; ++r)
                S16[B_S + (rt * 16 + lg * 4 + r) * 72 + hh * 16 + l15] =
                    (short)f2bf_u(oc[r] * inv[r]);
        }
    }
    __syncthreads();   // (2) all o written — LAST barrier

    // ================= Back half: wave w (<3) owns rows 16w..16w+15,
    // fully private: P4 + LN1(regs) + FF + LN2(regs) + store. No barriers.
    if (w < 3) {
        // ---- P4: out2 rows = o(rows) @ Wo^T, all 64 cols
        bf16x8 ao0 = *reinterpret_cast<const bf16x8*>(&S16[B_S + (w * 16 + l15) * 72 + lg * 8]);
        bf16x8 ao1 = *reinterpret_cast<const bf16x8*>(&S16[B_S + (w * 16 + l15) * 72 + 32 + lg * 8]);
        f32x4 c[4];
        #pragma unroll
        for (int nt = 0; nt < 4; ++nt) {
            bf16x8 bO0 = *reinterpret_cast<const bf16x8*>(&ws[WSO + (nt * 16 + l15) * 64 + lg * 8]);
            bf16x8 bO1 = *reinterpret_cast<const bf16x8*>(&ws[WSO + (nt * 16 + l15) * 64 + 32 + lg * 8]);
            f32x4 z = {0.f,0.f,0.f,0.f};
            c[nt] = __builtin_amdgcn_mfma_f32_16x16x32_bf16(ao0, bO0, z, 0, 0, 0);
            c[nt] = __builtin_amdgcn_mfma_f32_16x16x32_bf16(ao1, bO1, c[nt], 0, 0, 0);
        }
        float bo4[4], g1v[4], be1v[4];
        #pragma unroll
        for (int nt = 0; nt < 4; ++nt) {
            bo4[nt]  = bo[nt * 16 + l15];
            g1v[nt]  = ln1g[nt * 16 + l15];
            be1v[nt] = ln1b[nt * 16 + l15];
        }
        // ---- LN1 in registers (row = one 16-lane group); residual from qbf(A)
        float xres[4][4];   // [r][nt]
        #pragma unroll
        for (int r = 0; r < 4; ++r) {
            int row = w * 16 + lg * 4 + r;
            float v[4];
            #pragma unroll
            for (int nt = 0; nt < 4; ++nt) {
                unsigned int qb = (unsigned int)(unsigned short)S16[A_S + row * 72 + nt * 16 + l15];
                v[nt] = c[nt][r] + bo4[nt] + bits2f(qb << 16);
            }
            float s1 = (v[0] + v[1]) + (v[2] + v[3]);
            float s2 = (v[0]*v[0] + v[1]*v[1]) + (v[2]*v[2] + v[3]*v[3]);
            s1 += __shfl_xor(s1, 1); s1 += __shfl_xor(s1, 2);
            s1 += __shfl_xor(s1, 4); s1 += __shfl_xor(s1, 8);
            s2 += __shfl_xor(s2, 1); s2 += __shfl_xor(s2, 2);
            s2 += __shfl_xor(s2, 4); s2 += __shfl_xor(s2, 8);
            float mu  = s1 * (1.f / 64.f);
            float var = s2 * (1.f / 64.f) - mu * mu;
            float rs = __builtin_amdgcn_rsqf(var + EPSF);
            #pragma unroll
            for (int nt = 0; nt < 4; ++nt) {
                float x = (v[nt] - mu) * rs * g1v[nt] + be1v[nt];
                xres[r][nt] = x;
                S16[A_S + row * 72 + nt * 16 + l15] = (short)f2bf_u(x);
            }
        }
        // ---- FF over rows 16w..+15, all 256 hidden in 2 halves; h private
        f32x4 ffC[4];
        #pragma unroll
        for (int nt = 0; nt < 4; ++nt) ffC[nt] = (f32x4){0.f,0.f,0.f,0.f};
        bf16x8 aX0 = *reinterpret_cast<const bf16x8*>(&S16[A_S + (w * 16 + l15) * 72 + lg * 8]);
        bf16x8 aX1 = *reinterpret_cast<const bf16x8*>(&S16[A_S + (w * 16 + l15) * 72 + 32 + lg * 8]);
        #pragma unroll
        for (int hb = 0; hb < 2; ++hb) {
            #pragma unroll
            for (int j16 = 0; j16 < 8; ++j16) {
                int jrow = (hb * 8 + j16) * 16 + l15;
                bf16x8 b0 = *reinterpret_cast<const bf16x8*>(&ws[WS1 + jrow * 64 + lg * 8]);
                bf16x8 b1 = *reinterpret_cast<const bf16x8*>(&ws[WS1 + jrow * 64 + 32 + lg * 8]);
                float b1v = pb1[jrow];
                f32x4 z = {0.f,0.f,0.f,0.f};
                f32x4 ch = __builtin_amdgcn_mfma_f32_16x16x32_bf16(aX0, b0, z, 0, 0, 0);
                ch = __builtin_amdgcn_mfma_f32_16x16x32_bf16(aX1, b1, ch, 0, 0, 0);
                #pragma unroll
                for (int r = 0; r < 4; ++r)
                    S16[H_S + (w * 16 + lg * 4 + r) * 136 + j16 * 16 + l15] =
                        (short)f2bf_u(fmaxf(ch[r] + b1v, 0.f));
            }
            // FF2 for this half (reads own h rows; same-wave in-order)
            bf16x8 aH0 = *reinterpret_cast<const bf16x8*>(&S16[H_S + (w * 16 + l15) * 136 +  0 + lg * 8]);
            bf16x8 aH1 = *reinterpret_cast<const bf16x8*>(&S16[H_S + (w * 16 + l15) * 136 + 32 + lg * 8]);
            bf16x8 aH2 = *reinterpret_cast<const bf16x8*>(&S16[H_S + (w * 16 + l15) * 136 + 64 + lg * 8]);
            bf16x8 aH3 = *reinterpret_cast<const bf16x8*>(&S16[H_S + (w * 16 + l15) * 136 + 96 + lg * 8]);
            #pragma unroll
            for (int nt = 0; nt < 4; ++nt) {
                const int wb = WS2 + (nt * 16 + l15) * 256 + hb * 128;
                bf16x8 bw0 = *reinterpret_cast<const bf16x8*>(&ws[wb +  0 + lg * 8]);
                bf16x8 bw1 = *reinterpret_cast<const bf16x8*>(&ws[wb + 32 + lg * 8]);
                bf16x8 bw2 = *reinterpret_cast<const bf16x8*>(&ws[wb + 64 + lg * 8]);
                bf16x8 bw3 = *reinterpret_cast<const bf16x8*>(&ws[wb + 96 + lg * 8]);
                ffC[nt] = __builtin_amdgcn_mfma_f32_16x16x32_bf16(aH0, bw0, ffC[nt], 0, 0, 0);
                ffC[nt] = __builtin_amdgcn_mfma_f32_16x16x32_bf16(aH1, bw1, ffC[nt], 0, 0, 0);
                ffC[nt] = __builtin_amdgcn_mfma_f32_16x16x32_bf16(aH2, bw2, ffC[nt], 0, 0, 0);
                ffC[nt] = __builtin_amdgcn_mfma_f32_16x16x32_bf16(aH3, bw3, ffC[nt], 0, 0, 0);
            }
        }
        // ---- LN2 in registers + store
        float b2v4[4], g2v[4], be2v[4];
        #pragma unroll
        for (int nt = 0; nt < 4; ++nt) {
            b2v4[nt] = pb2[nt * 16 + l15];
            g2v[nt]  = ln2g[nt * 16 + l15];
            be2v[nt] = ln2b[nt * 16 + l15];
        }
        #pragma unroll
        for (int r = 0; r < 4; ++r) {
            int row = w * 16 + lg * 4 + r;
            float v[4];
            #pragma unroll
            for (int nt = 0; nt < 4; ++nt)
                v[nt] = ffC[nt][r] + b2v4[nt] + xres[r][nt];
            float s1 = (v[0] + v[1]) + (v[2] + v[3]);
            float s2 = (v[0]*v[0] + v[1]*v[1]) + (v[2]*v[2] + v[3]*v[3]);
            s1 += __shfl_xor(s1, 1); s1 += __shfl_xor(s1, 2);
            s1 += __shfl_xor(s1, 4); s1 += __shfl_xor(s1, 8);
            s2 += __shfl_xor(s2, 1); s2 += __shfl_xor(s2, 2);
            s2 += __shfl_xor(s2, 4); s2 += __shfl_xor(s2, 8);
            float mu  = s1 * (1.f / 64.f);
            float var = s2 * (1.f / 64.f) - mu * mu;
            float rs = __builtin_amdgcn_rsqf(var + EPSF);
            #pragma unroll
            for (int nt = 0; nt < 4; ++nt)
                out[gbase + row * 64 + nt * 16 + l15] =
                    (v[nt] - mu) * rs * g2v[nt] + be2v[nt];
        }
    }
}

extern "C" void kernel_launch(void* const* d_in, const int* in_sizes, int n_in,
                              void* d_out, int out_size, void* d_ws, size_t ws_size,
                              hipStream_t stream) {
    const float* value = (const float*)d_in[0];
    const float* keys  = (const float*)d_in[1];
    const float* query = (const float*)d_in[2];
    const float* Wv    = (const float*)d_in[3];
    const float* Wk    = (const float*)d_in[4];
    const float* Wq    = (const float*)d_in[5];
    const float* Wo    = (const float*)d_in[6];
    const float* bo    = (const float*)d_in[7];
    const float* temb  = (const float*)d_in[8];
    const float* ln1g  = (const float*)d_in[9];
    const float* ln1b  = (const float*)d_in[10];
    const float* ln2g  = (const float*)d_in[11];
    const float* ln2b  = (const float*)d_in[12];
    const float* W1    = (const float*)d_in[13];
    const float* b1    = (const float*)d_in[14];
    const float* W2    = (const float*)d_in[15];
    const float* b2    = (const float*)d_in[16];
    const int*   tq    = (const int*)d_in[17];
    float* outp = (float*)d_out;
    short* ws = (short*)d_ws;

    hipLaunchKernelGGL(wconv_kernel, dim3(147), dim3(256), 0, stream,
                       Wv, Wk, Wq, Wo, W1, W2, ws);
    hipLaunchKernelGGL(ttrans_kernel, dim3(NSEQ), dim3(256), 0, stream,
                       value, keys, query, bo, temb,
                       ln1g, ln1b, ln2g, ln2b, b1, b2, ws, tq, outp);
}

// Round 14
// 74.779 us; speedup vs baseline: 1.7548x; 1.7548x over previous
//
#include <hip/hip_runtime.h>
#include <hip/hip_bf16.h>
#include <math.h>

#define NSEQ 4096
#define TN 288
#define EPSF 1e-5f

typedef short bf16x8 __attribute__((ext_vector_type(8)));
typedef float f32x4 __attribute__((ext_vector_type(4)));

// ---- d_ws layout (shorts): preconverted bf16 weights ----
#define WSV 0        // Wv 16x16
#define WSK 256      // Wk 16x16
#define WSQ 512      // Wq 16x16  (PRE-SCALED by 0.125 = 1/sqrt(E))
#define WSO 768      // Wo 64x64 row-major
#define WS1 4864     // W1 256x64 row-major
#define WS2 21248    // W2 64x256 row-major

// ---- LDS pool: 27136 B ----
//  A [0,3456)      qbf -> qp (P1 in-place) -> xbf (LN1..LN2)     [48][72]
//  B [3456,6912)   kbf -> kp (P1 in-place) -> o (P2P3) -> ffo    [48][72]
//  C [6912,10496)  vbf [48][72] (dead after P1)
//  D [10496,13568) vpT [64][48] -> att [16][48] per-head OWN slice (no barrier:
//                  vA/vB are in registers before att overwrites the slice)
//  C+D span: out2 f32 [48][68] (P4->LN1), h [48][136] (FF)
#define A_S   0
#define B_S   3456
#define C_S   6912
#define D_S   10496
#define CD_F  3456    // float index of C_S
#define H_S   6912

__device__ __forceinline__ unsigned short f2bf_u(float f) {
    __hip_bfloat16 h = __float2bfloat16(f);
    return *reinterpret_cast<const unsigned short*>(&h);
}
__device__ __forceinline__ unsigned int pk2(float a, float b) {
    return (unsigned int)f2bf_u(a) | ((unsigned int)f2bf_u(b) << 16);
}
__device__ __forceinline__ float bits2f(unsigned int u) { return __uint_as_float(u); }

// ---------- prologue: f32 -> bf16 weight conversion into d_ws ----------
__global__ void wconv_kernel(const float* __restrict__ Wv, const float* __restrict__ Wk,
                             const float* __restrict__ Wq, const float* __restrict__ Wo,
                             const float* __restrict__ W1, const float* __restrict__ W2,
                             short* __restrict__ ws) {
    int i = blockIdx.x * 256 + threadIdx.x;   // 0..37631
    float v;
    if (i < 256)        v = Wv[i];
    else if (i < 512)   v = Wk[i - 256];
    else if (i < 768)   v = Wq[i - 512] * 0.125f;   // fold 1/sqrt(E) into Wq
    else if (i < 4864)  v = Wo[i - 768];
    else if (i < 21248) v = W1[i - 4864];
    else                v = W2[i - 21248];
    ws[i] = (short)f2bf_u(v);
}

__global__ __launch_bounds__(256, 5)
void ttrans_kernel(const float* __restrict__ value,
                   const float* __restrict__ keys,
                   const float* __restrict__ query,
                   const float* __restrict__ bo,
                   const float* __restrict__ temb,
                   const float* __restrict__ ln1g,
                   const float* __restrict__ ln1b,
                   const float* __restrict__ ln2g,
                   const float* __restrict__ ln2b,
                   const float* __restrict__ pb1,
                   const float* __restrict__ pb2,
                   const short* __restrict__ ws,
                   const int* __restrict__ tqp,
                   float* __restrict__ out)
{
    __shared__ __align__(16) unsigned char smem[27136];
    short* S16 = reinterpret_cast<short*>(smem);
    float* S32 = reinterpret_cast<float*>(smem);

    const int tid  = threadIdx.x;
    const int lane = tid & 63;
    const int w    = tid >> 6;           // wave 0..3 (= head in P1-P3)
    const int l15  = lane & 15;
    const int lg   = lane >> 4;
    const int n    = blockIdx.x;
    const size_t gbase = (size_t)n * 3072;
    const int tqv  = *tqp;
    const int c4   = (lane & 15) * 4;    // 4-col base for P0/LN phases
    const int rg   = lane >> 4;          // row-in-group 0..3
    const int hh   = w;

    // ================= P0: coalesced float4 load q,k,v (+temb) -> bf16 LDS;
    //                  q residual kept in registers (f32, exact).
    float4 qres4[3];
    {
        int t = w * 12 + rg;
        int ti = ((tqv % TN) + TN + t) % TN;
        #pragma unroll
        for (int it = 0; it < 3; ++it) {
            float4 tv = *reinterpret_cast<const float4*>(&temb[ti * 64 + c4]);
            float4 qv = *reinterpret_cast<const float4*>(&query[gbase + t * 64 + c4]);
            float4 kv = *reinterpret_cast<const float4*>(&keys [gbase + t * 64 + c4]);
            float4 vv = *reinterpret_cast<const float4*>(&value[gbase + t * 64 + c4]);
            float4 qq = make_float4(qv.x + tv.x, qv.y + tv.y, qv.z + tv.z, qv.w + tv.w);
            float4 kk = make_float4(kv.x + tv.x, kv.y + tv.y, kv.z + tv.z, kv.w + tv.w);
            qres4[it] = qq;
            *reinterpret_cast<uint2*>(&S16[A_S + t * 72 + c4]) =
                make_uint2(pk2(qq.x, qq.y), pk2(qq.z, qq.w));
            *reinterpret_cast<uint2*>(&S16[B_S + t * 72 + c4]) =
                make_uint2(pk2(kk.x, kk.y), pk2(kk.z, kk.w));
            *reinterpret_cast<uint2*>(&S16[C_S + t * 72 + c4]) =
                make_uint2(pk2(vv.x, vv.y), pk2(vv.z, vv.w));
            t += 4; ti += 4; if (ti >= TN) ti -= TN;
        }
    }
    __syncthreads();   // (0)

    // ================= P1: per-head projections; qp/kp IN-PLACE over qbf/kbf.
    {
        bf16x8 bWv = {}, bWk = {}, bWq = {};
        if (lane < 32) {
            bWv = *reinterpret_cast<const bf16x8*>(&ws[WSV + l15 * 16 + lg * 8]);
            bWk = *reinterpret_cast<const bf16x8*>(&ws[WSK + l15 * 16 + lg * 8]);
            bWq = *reinterpret_cast<const bf16x8*>(&ws[WSQ + l15 * 16 + lg * 8]);
        }
        #pragma unroll
        for (int rt = 0; rt < 3; ++rt) {
            bf16x8 aQ = {}, aK = {}, aV = {};
            if (lane < 32) {
                int ro = (rt * 16 + l15) * 72 + hh * 16 + lg * 8;
                aQ = *reinterpret_cast<const bf16x8*>(&S16[A_S + ro]);
                aK = *reinterpret_cast<const bf16x8*>(&S16[B_S + ro]);
                aV = *reinterpret_cast<const bf16x8*>(&S16[C_S + ro]);
            }
            f32x4 z = {0.f,0.f,0.f,0.f};
            f32x4 cQ = __builtin_amdgcn_mfma_f32_16x16x32_bf16(aQ, bWq, z, 0, 0, 0);
            f32x4 cK = __builtin_amdgcn_mfma_f32_16x16x32_bf16(aK, bWk, z, 0, 0, 0);
            f32x4 cV = __builtin_amdgcn_mfma_f32_16x16x32_bf16(aV, bWv, z, 0, 0, 0);
            #pragma unroll
            for (int r = 0; r < 4; ++r) {
                int row = rt * 16 + lg * 4 + r;
                S16[A_S + row * 72 + hh * 16 + l15] = (short)f2bf_u(cQ[r]);
                S16[B_S + row * 72 + hh * 16 + l15] = (short)f2bf_u(cK[r]);
                S16[D_S + (hh * 16 + l15) * 48 + row] = (short)f2bf_u(cV[r]);
            }
        }
    }
    // NO barrier: P2/P3 consume only this wave's per-head regions (qp/kp cols,
    // own vpT slice in D; att overlays the OWN slice after vA/vB are in regs)

    // ================= P2+P3 fused per 16-query block (wave w = head w)
    // causal dead-block skip + defer-normalize (r11); att in own D slice
    {
        const float PEXP = 0.006737946999085467f;            // e^-5
        const unsigned short PBF = f2bf_u(PEXP);
        bf16x8 bK0 = {}, bK1 = {}, bK2 = {};
        if (lane < 32) {
            bK0 = *reinterpret_cast<const bf16x8*>(&S16[B_S + ( 0 + l15) * 72 + hh * 16 + lg * 8]);
            bK1 = *reinterpret_cast<const bf16x8*>(&S16[B_S + (16 + l15) * 72 + hh * 16 + lg * 8]);
            bK2 = *reinterpret_cast<const bf16x8*>(&S16[B_S + (32 + l15) * 72 + hh * 16 + lg * 8]);
        }
        bf16x8 vA = *reinterpret_cast<const bf16x8*>(&S16[D_S + (hh * 16 + l15) * 48 + lg * 8]);
        bf16x8 vB = {};
        if (lane < 32)
            vB = *reinterpret_cast<const bf16x8*>(&S16[D_S + (hh * 16 + l15) * 48 + 32 + lg * 8]);
        // pin the vpT reads before att overwrites the same slice (WAR, same wave)
        asm volatile("" ::: "memory");

        const int abase = D_S + hh * 768;    // att [16][48] over own vpT slice
        #pragma unroll
        for (int rt = 0; rt < 3; ++rt) {
            bf16x8 aQ = {};
            if (lane < 32)
                aQ = *reinterpret_cast<const bf16x8*>(&S16[A_S + (rt * 16 + l15) * 72 + hh * 16 + lg * 8]);
            f32x4 z = {0.f,0.f,0.f,0.f};
            f32x4 e0 = __builtin_amdgcn_mfma_f32_16x16x32_bf16(aQ, bK0, z, 0, 0, 0);
            f32x4 e1 = z, e2 = z;
            if (rt >= 1) e1 = __builtin_amdgcn_mfma_f32_16x16x32_bf16(aQ, bK1, z, 0, 0, 0);
            if (rt == 2) e2 = __builtin_amdgcn_mfma_f32_16x16x32_bf16(aQ, bK2, z, 0, 0, 0);
            float inv[4];
            #pragma unroll
            for (int r = 0; r < 4; ++r) {
                int tl = lg * 4 + r;            // row within qblock
                int t = rt * 16 + tl;           // global query index
                float p0, p1, p2;
                float v0 = fminf(5.f, fmaxf(-5.f, e0[r]));
                if (rt == 0) v0 = (l15 <= t) ? v0 : -5.f;
                p0 = __expf(v0);
                S16[abase + tl * 48 + l15] = (short)f2bf_u(p0);
                if (rt == 0) {
                    p1 = PEXP;
                    S16[abase + tl * 48 + 16 + l15] = (short)PBF;
                } else {
                    float v1 = fminf(5.f, fmaxf(-5.f, e1[r]));
                    if (rt == 1) v1 = (16 + l15 <= t) ? v1 : -5.f;
                    p1 = __expf(v1);
                    S16[abase + tl * 48 + 16 + l15] = (short)f2bf_u(p1);
                }
                if (rt < 2) {
                    p2 = PEXP;
                    S16[abase + tl * 48 + 32 + l15] = (short)PBF;
                } else {
                    float v2c = fminf(5.f, fmaxf(-5.f, e2[r]));
                    v2c = (32 + l15 <= t) ? v2c : -5.f;
                    p2 = __expf(v2c);
                    S16[abase + tl * 48 + 32 + l15] = (short)f2bf_u(p2);
                }
                float s = p0 + p1 + p2;
                s += __shfl_xor(s, 1);
                s += __shfl_xor(s, 2);
                s += __shfl_xor(s, 4);
                s += __shfl_xor(s, 8);
                inv[r] = __builtin_amdgcn_rcpf(s);
            }
            // PV for this qblock (same-wave in-order DS); scale by inv at output
            bf16x8 a0 = *reinterpret_cast<const bf16x8*>(&S16[abase + l15 * 48 + lg * 8]);
            bf16x8 a1 = {};
            if (lane < 32)
                a1 = *reinterpret_cast<const bf16x8*>(&S16[abase + l15 * 48 + 32 + lg * 8]);
            f32x4 zz = {0.f,0.f,0.f,0.f};
            f32x4 oc = __builtin_amdgcn_mfma_f32_16x16x32_bf16(a0, vA, zz, 0, 0, 0);
            oc = __builtin_amdgcn_mfma_f32_16x16x32_bf16(a1, vB, oc, 0, 0, 0);
            #pragma unroll
            for (int r = 0; r < 4; ++r)
                S16[B_S + (rt * 16 + lg * 4 + r) * 72 + hh * 16 + l15] =
                    (short)f2bf_u(oc[r] * inv[r]);
        }
    }
    __syncthreads();   // (1) P4 reads all heads' o columns

    // ================= P4: out2 = o @ Wo^T + bo -> f32 [48][68] over C+D
    {
        bf16x8 bO0 = *reinterpret_cast<const bf16x8*>(&ws[WSO + (w * 16 + l15) * 64 + lg * 8]);
        bf16x8 bO1 = *reinterpret_cast<const bf16x8*>(&ws[WSO + (w * 16 + l15) * 64 + 32 + lg * 8]);
        const float bo_v = bo[w * 16 + l15];
        #pragma unroll
        for (int mt = 0; mt < 3; ++mt) {
            bf16x8 a0 = *reinterpret_cast<const bf16x8*>(&S16[B_S + (mt * 16 + l15) * 72 + lg * 8]);
            bf16x8 a1 = *reinterpret_cast<const bf16x8*>(&S16[B_S + (mt * 16 + l15) * 72 + 32 + lg * 8]);
            f32x4 c = {0.f,0.f,0.f,0.f};
            c = __builtin_amdgcn_mfma_f32_16x16x32_bf16(a0, bO0, c, 0, 0, 0);
            c = __builtin_amdgcn_mfma_f32_16x16x32_bf16(a1, bO1, c, 0, 0, 0);
            #pragma unroll
            for (int r = 0; r < 4; ++r)
                S32[CD_F + (mt * 16 + lg * 4 + r) * 68 + w * 16 + l15] = c[r] + bo_v;
        }
    }
    __syncthreads();   // (2)

    // ================= LN1: 16-lane-row groups, 4 cols/lane; E[x^2]-mu^2
    {
        float4 g1 = *reinterpret_cast<const float4*>(&ln1g[c4]);
        float4 be1 = *reinterpret_cast<const float4*>(&ln1b[c4]);
        #pragma unroll
        for (int it = 0; it < 3; ++it) {
            int t = w * 12 + it * 4 + rg;
            float4 o = *reinterpret_cast<const float4*>(&S32[CD_F + t * 68 + c4]);
            float v0 = o.x + qres4[it].x, v1 = o.y + qres4[it].y;
            float v2 = o.z + qres4[it].z, v3 = o.w + qres4[it].w;
            float s1 = (v0 + v1) + (v2 + v3);
            float s2 = (v0 * v0 + v1 * v1) + (v2 * v2 + v3 * v3);
            s1 += __shfl_xor(s1, 1); s1 += __shfl_xor(s1, 2);
            s1 += __shfl_xor(s1, 4); s1 += __shfl_xor(s1, 8);
            s2 += __shfl_xor(s2, 1); s2 += __shfl_xor(s2, 2);
            s2 += __shfl_xor(s2, 4); s2 += __shfl_xor(s2, 8);
            float mu  = s1 * (1.f / 64.f);
            float var = s2 * (1.f / 64.f) - mu * mu;
            float rs = __builtin_amdgcn_rsqf(var + EPSF);
            float x0 = (v0 - mu) * rs * g1.x + be1.x;
            float x1 = (v1 - mu) * rs * g1.y + be1.y;
            float x2 = (v2 - mu) * rs * g1.z + be1.z;
            float x3 = (v3 - mu) * rs * g1.w + be1.w;
            *reinterpret_cast<uint2*>(&S16[A_S + t * 72 + c4]) =
                make_uint2(pk2(x0, x1), pk2(x2, x3));
        }
    }
    __syncthreads();   // (3)

    // ================= FF in two 128-wide halves; h [48][136] over C+D
    f32x4 ffC[3];
    #pragma unroll
    for (int mt = 0; mt < 3; ++mt) ffC[mt] = (f32x4){0.f,0.f,0.f,0.f};

    #pragma unroll
    for (int hb = 0; hb < 2; ++hb) {
        // FF1: wave w handles local j16 in {2w, 2w+1}
        #pragma unroll
        for (int jj = 0; jj < 2; ++jj) {
            int j16 = w * 2 + jj;             // 0..7 within half
            int jrow = (hb * 8 + j16) * 16 + l15;
            bf16x8 b0 = *reinterpret_cast<const bf16x8*>(&ws[WS1 + jrow * 64 + lg * 8]);
            bf16x8 b1 = *reinterpret_cast<const bf16x8*>(&ws[WS1 + jrow * 64 + 32 + lg * 8]);
            float b1v = pb1[jrow];
            #pragma unroll
            for (int mt = 0; mt < 3; ++mt) {
                bf16x8 a0 = *reinterpret_cast<const bf16x8*>(&S16[A_S + (mt * 16 + l15) * 72 + lg * 8]);
                bf16x8 a1 = *reinterpret_cast<const bf16x8*>(&S16[A_S + (mt * 16 + l15) * 72 + 32 + lg * 8]);
                f32x4 c = {0.f,0.f,0.f,0.f};
                c = __builtin_amdgcn_mfma_f32_16x16x32_bf16(a0, b0, c, 0, 0, 0);
                c = __builtin_amdgcn_mfma_f32_16x16x32_bf16(a1, b1, c, 0, 0, 0);
                #pragma unroll
                for (int r = 0; r < 4; ++r)
                    S16[H_S + (mt * 16 + lg * 4 + r) * 136 + j16 * 16 + l15] =
                        (short)f2bf_u(fmaxf(c[r] + b1v, 0.f));
            }
        }
        __syncthreads();   // (4)/(6)

        // FF2: accumulate this half's contribution
        {
            const int wb = WS2 + (w * 16 + l15) * 256 + hb * 128;
            bf16x8 bw0 = *reinterpret_cast<const bf16x8*>(&ws[wb +  0 + lg * 8]);
            bf16x8 bw1 = *reinterpret_cast<const bf16x8*>(&ws[wb + 32 + lg * 8]);
            bf16x8 bw2 = *reinterpret_cast<const bf16x8*>(&ws[wb + 64 + lg * 8]);
            bf16x8 bw3 = *reinterpret_cast<const bf16x8*>(&ws[wb + 96 + lg * 8]);
            #pragma unroll
            for (int mt = 0; mt < 3; ++mt) {
                bf16x8 a0 = *reinterpret_cast<const bf16x8*>(&S16[H_S + (mt * 16 + l15) * 136 +  0 + lg * 8]);
                bf16x8 a1 = *reinterpret_cast<const bf16x8*>(&S16[H_S + (mt * 16 + l15) * 136 + 32 + lg * 8]);
                bf16x8 a2 = *reinterpret_cast<const bf16x8*>(&S16[H_S + (mt * 16 + l15) * 136 + 64 + lg * 8]);
                bf16x8 a3 = *reinterpret_cast<const bf16x8*>(&S16[H_S + (mt * 16 + l15) * 136 + 96 + lg * 8]);
                ffC[mt] = __builtin_amdgcn_mfma_f32_16x16x32_bf16(a0, bw0, ffC[mt], 0, 0, 0);
                ffC[mt] = __builtin_amdgcn_mfma_f32_16x16x32_bf16(a1, bw1, ffC[mt], 0, 0, 0);
                ffC[mt] = __builtin_amdgcn_mfma_f32_16x16x32_bf16(a2, bw2, ffC[mt], 0, 0, 0);
                ffC[mt] = __builtin_amdgcn_mfma_f32_16x16x32_bf16(a3, bw3, ffC[mt], 0, 0, 0);
            }
        }
        if (hb == 0) __syncthreads();   // (5) protect h before rewrite
    }

    // bias + store ffo into B (h untouched; same-wave order)
    {
        float b2v = pb2[w * 16 + l15];
        #pragma unroll
        for (int mt = 0; mt < 3; ++mt)
            #pragma unroll
            for (int r = 0; r < 4; ++r)
                S16[B_S + (mt * 16 + lg * 4 + r) * 72 + w * 16 + l15] =
                    (short)f2bf_u(ffC[mt][r] + b2v);
    }
    __syncthreads();   // (7)

    // ================= LN2 + store: 16-lane-row groups, 4 cols/lane
    {
        float4 g2 = *reinterpret_cast<const float4*>(&ln2g[c4]);
        float4 be2 = *reinterpret_cast<const float4*>(&ln2b[c4]);
        #pragma unroll
        for (int it = 0; it < 3; ++it) {
            int t = w * 12 + it * 4 + rg;
            uint2 fp = *reinterpret_cast<const uint2*>(&S16[B_S + t * 72 + c4]);
            uint2 xp = *reinterpret_cast<const uint2*>(&S16[A_S + t * 72 + c4]);
            float v0 = bits2f(fp.x << 16) + bits2f(xp.x << 16);
            float v1 = bits2f(fp.x & 0xffff0000u) + bits2f(xp.x & 0xffff0000u);
            float v2 = bits2f(fp.y << 16) + bits2f(xp.y << 16);
            float v3 = bits2f(fp.y & 0xffff0000u) + bits2f(xp.y & 0xffff0000u);
            float s1 = (v0 + v1) + (v2 + v3);
            float s2 = (v0 * v0 + v1 * v1) + (v2 * v2 + v3 * v3);
            s1 += __shfl_xor(s1, 1); s1 += __shfl_xor(s1, 2);
            s1 += __shfl_xor(s1, 4); s1 += __shfl_xor(s1, 8);
            s2 += __shfl_xor(s2, 1); s2 += __shfl_xor(s2, 2);
            s2 += __shfl_xor(s2, 4); s2 += __shfl_xor(s2, 8);
            float mu  = s1 * (1.f / 64.f);
            float var = s2 * (1.f / 64.f) - mu * mu;
            float rs = __builtin_amdgcn_rsqf(var + EPSF);
            float y0 = (v0 - mu) * rs * g2.x + be2.x;
            float y1 = (v1 - mu) * rs * g2.y + be2.y;
            float y2 = (v2 - mu) * rs * g2.z + be2.z;
            float y3 = (v3 - mu) * rs * g2.w + be2.w;
            *reinterpret_cast<float4*>(&out[gbase + t * 64 + c4]) =
                make_float4(y0, y1, y2, y3);
        }
    }
}

extern "C" void kernel_launch(void* const* d_in, const int* in_sizes, int n_in,
                              void* d_out, int out_size, void* d_ws, size_t ws_size,
                              hipStream_t stream) {
    const float* value = (const float*)d_in[0];
    const float* keys  = (const float*)d_in[1];
    const float* query = (const float*)d_in[2];
    const float* Wv    = (const float*)d_in[3];
    const float* Wk    = (const float*)d_in[4];
    const float* Wq    = (const float*)d_in[5];
    const float* Wo    = (const float*)d_in[6];
    const float* bo    = (const float*)d_in[7];
    const float* temb  = (const float*)d_in[8];
    const float* ln1g  = (const float*)d_in[9];
    const float* ln1b  = (const float*)d_in[10];
    const float* ln2g  = (const float*)d_in[11];
    const float* ln2b  = (const float*)d_in[12];
    const float* W1    = (const float*)d_in[13];
    const float* b1    = (const float*)d_in[14];
    const float* W2    = (const float*)d_in[15];
    const float* b2    = (const float*)d_in[16];
    const int*   tq    = (const int*)d_in[17];
    float* outp = (float*)d_out;
    short* ws = (short*)d_ws;

    hipLaunchKernelGGL(wconv_kernel, dim3(147), dim3(256), 0, stream,
                       Wv, Wk, Wq, Wo, W1, W2, ws);
    hipLaunchKernelGGL(ttrans_kernel, dim3(NSEQ), dim3(256), 0, stream,
                       value, keys, query, bo, temb,
                       ln1g, ln1b, ln2g, ln2b, b1, b2, ws, tq, outp);
}